// Round 1
// baseline (125.789 us; speedup 1.0000x reference)
//
#include <hip/hip_runtime.h>
#include <math.h>

// ---------------------------------------------------------------------------
// CAGPool layer, MI355X. Outputs concatenated flat as float32 values:
//   [0]                : x_out      [B*k, D]
//   [B*k*D]            : edge_index_new [2, E]  (ids as floats, -1 for dropped)
//   [+2E]              : batch_out  [B*k]
//   [+B*k]             : perm       [B*k]
//   [+B*k]             : valid      [E]   (0.0 / 1.0)
//
// Ordering must match jax.lax.top_k exactly (descending score, ties -> lower
// index). Scores computed in float64 so ordering is immune to f32 summation-
// order noise vs the numpy reference.
// ---------------------------------------------------------------------------

// --- kernel 1: per-graph 1/||pool_vector[b]||, double precision -------------
__global__ void norm_kernel(const float* __restrict__ pool,
                            double* __restrict__ inv_norm, int D) {
    int b = blockIdx.x;
    int l = threadIdx.x;                   // 64 threads = 1 wave
    double acc = 0.0;
    for (int j = l; j < D; j += 64) {
        double v = (double)pool[(size_t)b * D + j];
        acc += v * v;
    }
    for (int off = 32; off > 0; off >>= 1) acc += __shfl_down(acc, off, 64);
    if (l == 0) inv_norm[b] = 1.0 / sqrt(acc);
}

// --- kernel 2: score[i] = dot(x[i], pool[b]) / ||pool[b]||, double ---------
__global__ void score_kernel(const float* __restrict__ x,
                             const float* __restrict__ pool,
                             const double* __restrict__ inv_norm,
                             double* __restrict__ scores,
                             int D, int n) {
    int node = blockIdx.x * 4 + (threadIdx.x >> 6);   // 4 waves/block
    int l = threadIdx.x & 63;
    int b = node / n;
    const float* xr = x + (size_t)node * D;
    const float* pr = pool + (size_t)b * D;
    double acc = 0.0;
    for (int j = l; j < D; j += 64)
        acc += (double)xr[j] * (double)pr[j];
    for (int off = 32; off > 0; off >>= 1) acc += __shfl_down(acc, off, 64);
    if (l == 0) scores[node] = acc * inv_norm[b];
}

// --- kernel 3: per-graph exact top-k rank (O(n^2) count), write maps --------
__global__ void rank_kernel(const double* __restrict__ scores,
                            int* __restrict__ nodemap,
                            int* __restrict__ perm_int,
                            float* __restrict__ out,
                            long off_batch, long off_perm,
                            int n, int k) {
    extern __shared__ double s[];
    int b = blockIdx.x;
    int t = threadIdx.x;                  // block = n threads
    int gid = b * n + t;
    double st = scores[gid];
    s[t] = st;
    __syncthreads();
    int rank = 0;
    for (int j = 0; j < n; ++j) {
        double sj = s[j];
        rank += (int)((sj > st) || (sj == st && j < t));
    }
    if (rank < k) {
        int p = b * k + rank;
        nodemap[gid] = p;
        perm_int[p] = gid;
        out[off_batch + p] = (float)b;
        out[off_perm + p]  = (float)gid;
    } else {
        nodemap[gid] = -1;
    }
}

// --- kernel 4: x_out[p] = x[perm[p]] * sigmoid(score[perm[p]]) --------------
__global__ void gather_kernel(const float* __restrict__ x,
                              const double* __restrict__ scores,
                              const int* __restrict__ perm_int,
                              float* __restrict__ out0, int D) {
    int p = blockIdx.x;
    int l = threadIdx.x;                  // 64 threads
    int gid = perm_int[p];
    double sc = scores[gid];
    float g = (float)(1.0 / (1.0 + exp(-sc)));
    const float4* xr = (const float4*)(x + (size_t)gid * D);
    float4* orow = (float4*)(out0 + (size_t)p * D);
    int nv = D >> 2;                      // D/4 float4 per row
    for (int j = l; j < nv; j += 64) {
        float4 v = xr[j];
        v.x *= g; v.y *= g; v.z *= g; v.w *= g;
        orow[j] = v;
    }
}

// --- kernel 5: edge remap + validity ---------------------------------------
__global__ void edge_kernel(const int* __restrict__ ei,
                            const int* __restrict__ nodemap,
                            float* __restrict__ out,
                            long off_e, long off_valid, long E) {
    long e = (long)blockIdx.x * blockDim.x + threadIdx.x;
    if (e >= E) return;
    int r = nodemap[ei[e]];
    int c = nodemap[ei[E + e]];
    bool valid = (r >= 0) && (c >= 0);
    out[off_e + e]     = valid ? (float)r : -1.0f;
    out[off_e + E + e] = valid ? (float)c : -1.0f;
    out[off_valid + e] = valid ? 1.0f : 0.0f;
}

extern "C" void kernel_launch(void* const* d_in, const int* in_sizes, int n_in,
                              void* d_out, int out_size, void* d_ws, size_t ws_size,
                              hipStream_t stream) {
    const float* x    = (const float*)d_in[0];
    const int*   ei   = (const int*)d_in[1];
    // const int* batch = (const int*)d_in[2];   // uniform sizes: b = i / n
    const float* pool = (const float*)d_in[3];
    // const int* c_size = (const int*)d_in[4];

    const int B = in_sizes[4];
    const int D = in_sizes[3] / B;
    const long N = (long)in_sizes[0] / D;
    const long E = (long)in_sizes[1] / 2;
    const int n = (int)(N / B);
    const int k = (n + 1) / 2;            // ceil(0.5 * n)

    // workspace layout (aligned)
    char* ws = (char*)d_ws;
    double* scores   = (double*)ws;                         ws += (size_t)N * 8;
    double* inv_norm = (double*)ws;                         ws += (size_t)B * 8;
    int*    nodemap  = (int*)ws;                            ws += (size_t)N * 4;
    int*    perm_int = (int*)ws;

    float* out = (float*)d_out;
    const long o0 = 0;                       // x_out [B*k, D]
    const long o1 = o0 + (long)B * k * D;    // edge_index_new [2, E]
    const long o2 = o1 + 2 * E;              // batch_out [B*k]
    const long o3 = o2 + (long)B * k;        // perm [B*k]
    const long o4 = o3 + (long)B * k;        // valid [E]

    norm_kernel<<<B, 64, 0, stream>>>(pool, inv_norm, D);
    score_kernel<<<(int)(N / 4), 256, 0, stream>>>(x, pool, inv_norm, scores, D, n);
    rank_kernel<<<B, n, (size_t)n * sizeof(double), stream>>>(
        scores, nodemap, perm_int, out, o2, o3, n, k);
    gather_kernel<<<B * k, 64, 0, stream>>>(x, scores, perm_int, out + o0, D);
    edge_kernel<<<(int)((E + 255) / 256), 256, 0, stream>>>(
        ei, nodemap, out, o1, o4, E);
}

// Round 2
// 103.023 us; speedup vs baseline: 1.2210x; 1.2210x over previous
//
#include <hip/hip_runtime.h>
#include <math.h>

// ---------------------------------------------------------------------------
// CAGPool layer, MI355X. Outputs concatenated flat as float32 values:
//   [0]      : x_out          [B*k, D]
//   [o1]     : edge_index_new [2, E]  (ids as floats, -1 for dropped)
//   [o2]     : batch_out      [B*k]
//   [o3]     : perm           [B*k]
//   [o4]     : valid          [E]   (0.0 / 1.0)
//
// Ordering must match jax.lax.top_k exactly (descending score, ties -> lower
// index). Scores computed in float64 so ordering is immune to f32 summation-
// order noise vs the numpy reference.
// ---------------------------------------------------------------------------

// --- kernel 1: per-graph 1/||pool_vector[b]||, double precision -------------
__global__ void norm_kernel(const float* __restrict__ pool,
                            double* __restrict__ inv_norm, int D) {
    int b = blockIdx.x;
    int l = threadIdx.x;                   // 64 threads = 1 wave
    double acc = 0.0;
    for (int j = l; j < D; j += 64) {
        double v = (double)pool[(size_t)b * D + j];
        acc += v * v;
    }
    for (int off = 32; off > 0; off >>= 1) acc += __shfl_down(acc, off, 64);
    if (l == 0) inv_norm[b] = 1.0 / sqrt(acc);
}

// --- kernel 2: score[i] = dot(x[i], pool[b]) / ||pool[b]||, double ---------
// One wave per node; lane l loads float4 -> whole 1KB row in ONE vmem instr.
__global__ void score_kernel(const float* __restrict__ x,
                             const float* __restrict__ pool,
                             const double* __restrict__ inv_norm,
                             double* __restrict__ scores,
                             int D, int n) {
    int node = blockIdx.x * 4 + (threadIdx.x >> 6);   // 4 waves/block
    int l = threadIdx.x & 63;
    int b = node / n;
    const float4* xr = (const float4*)(x + (size_t)node * D);
    const float4* pr = (const float4*)(pool + (size_t)b * D);
    int nv = D >> 2;
    double acc = 0.0;
    for (int j = l; j < nv; j += 64) {
        float4 xv = xr[j];
        float4 pv = pr[j];
        acc += (double)xv.x * (double)pv.x + (double)xv.y * (double)pv.y
             + (double)xv.z * (double)pv.z + (double)xv.w * (double)pv.w;
    }
    for (int off = 32; off > 0; off >>= 1) acc += __shfl_down(acc, off, 64);
    if (l == 0) scores[node] = acc * inv_norm[b];
}

// --- kernel 3: per-graph exact top-k rank (O(n^2) count), write maps --------
__global__ void rank_kernel(const double* __restrict__ scores,
                            int* __restrict__ nodemap,
                            int* __restrict__ perm_int,
                            float* __restrict__ out,
                            long off_batch, long off_perm,
                            int n, int k) {
    extern __shared__ double s[];
    int b = blockIdx.x;
    int t = threadIdx.x;                  // block = n threads
    int gid = b * n + t;
    double st = scores[gid];
    s[t] = st;
    __syncthreads();
    int rank = 0;
    for (int j = 0; j < n; ++j) {
        double sj = s[j];
        rank += (int)((sj > st) || (sj == st && j < t));
    }
    if (rank < k) {
        int p = b * k + rank;
        nodemap[gid] = p;
        perm_int[p] = gid;
        out[off_batch + p] = (float)b;
        out[off_perm + p]  = (float)gid;
    } else {
        nodemap[gid] = -1;
    }
}

// --- kernel 4: x_out[p] = x[perm[p]] * sigmoid(score[perm[p]]) --------------
// 256-thread block = 4 waves, one row per wave, one float4 per lane.
__global__ void gather_kernel(const float* __restrict__ x,
                              const double* __restrict__ scores,
                              const int* __restrict__ perm_int,
                              float* __restrict__ out0, int D) {
    int p = blockIdx.x * 4 + (threadIdx.x >> 6);
    int l = threadIdx.x & 63;
    int gid = perm_int[p];
    double sc = scores[gid];
    float g = (float)(1.0 / (1.0 + exp(-sc)));
    const float4* xr = (const float4*)(x + (size_t)gid * D);
    float4* orow = (float4*)(out0 + (size_t)p * D);
    int nv = D >> 2;
    for (int j = l; j < nv; j += 64) {
        float4 v = xr[j];
        v.x *= g; v.y *= g; v.z *= g; v.w *= g;
        orow[j] = v;
    }
}

// --- kernel 5: edge remap + validity, 4 edges/thread, 16B I/O ---------------
__global__ void edge_kernel4(const int4* __restrict__ ei_src,
                             const int4* __restrict__ ei_dst,
                             const int* __restrict__ nodemap,
                             float4* __restrict__ out_row,
                             float4* __restrict__ out_col,
                             float4* __restrict__ out_valid, long E4) {
    long e = (long)blockIdx.x * blockDim.x + threadIdx.x;
    if (e >= E4) return;
    int4 s = ei_src[e];
    int4 d = ei_dst[e];
    int r0 = nodemap[s.x], r1 = nodemap[s.y], r2 = nodemap[s.z], r3 = nodemap[s.w];
    int c0 = nodemap[d.x], c1 = nodemap[d.y], c2 = nodemap[d.z], c3 = nodemap[d.w];
    bool v0 = (r0 >= 0) & (c0 >= 0);
    bool v1 = (r1 >= 0) & (c1 >= 0);
    bool v2 = (r2 >= 0) & (c2 >= 0);
    bool v3 = (r3 >= 0) & (c3 >= 0);
    float4 rv = { v0 ? (float)r0 : -1.0f, v1 ? (float)r1 : -1.0f,
                  v2 ? (float)r2 : -1.0f, v3 ? (float)r3 : -1.0f };
    float4 cv = { v0 ? (float)c0 : -1.0f, v1 ? (float)c1 : -1.0f,
                  v2 ? (float)c2 : -1.0f, v3 ? (float)c3 : -1.0f };
    float4 vv = { v0 ? 1.0f : 0.0f, v1 ? 1.0f : 0.0f,
                  v2 ? 1.0f : 0.0f, v3 ? 1.0f : 0.0f };
    out_row[e]   = rv;
    out_col[e]   = cv;
    out_valid[e] = vv;
}

// scalar fallback (alignment/tail safety; not used for this instance's sizes)
__global__ void edge_kernel(const int* __restrict__ ei,
                            const int* __restrict__ nodemap,
                            float* __restrict__ out,
                            long off_e, long off_valid, long E) {
    long e = (long)blockIdx.x * blockDim.x + threadIdx.x;
    if (e >= E) return;
    int r = nodemap[ei[e]];
    int c = nodemap[ei[E + e]];
    bool valid = (r >= 0) && (c >= 0);
    out[off_e + e]     = valid ? (float)r : -1.0f;
    out[off_e + E + e] = valid ? (float)c : -1.0f;
    out[off_valid + e] = valid ? 1.0f : 0.0f;
}

extern "C" void kernel_launch(void* const* d_in, const int* in_sizes, int n_in,
                              void* d_out, int out_size, void* d_ws, size_t ws_size,
                              hipStream_t stream) {
    const float* x    = (const float*)d_in[0];
    const int*   ei   = (const int*)d_in[1];
    // const int* batch = (const int*)d_in[2];   // uniform sizes: b = i / n
    const float* pool = (const float*)d_in[3];
    // const int* c_size = (const int*)d_in[4];

    const int B = in_sizes[4];
    const int D = in_sizes[3] / B;
    const long N = (long)in_sizes[0] / D;
    const long E = (long)in_sizes[1] / 2;
    const int n = (int)(N / B);
    const int k = (n + 1) / 2;            // ceil(0.5 * n)

    // workspace layout (aligned)
    char* ws = (char*)d_ws;
    double* scores   = (double*)ws;                         ws += (size_t)N * 8;
    double* inv_norm = (double*)ws;                         ws += (size_t)B * 8;
    int*    nodemap  = (int*)ws;                            ws += (size_t)N * 4;
    int*    perm_int = (int*)ws;

    float* out = (float*)d_out;
    const long o0 = 0;                       // x_out [B*k, D]
    const long o1 = o0 + (long)B * k * D;    // edge_index_new [2, E]
    const long o2 = o1 + 2 * E;              // batch_out [B*k]
    const long o3 = o2 + (long)B * k;        // perm [B*k]
    const long o4 = o3 + (long)B * k;        // valid [E]

    norm_kernel<<<B, 64, 0, stream>>>(pool, inv_norm, D);
    score_kernel<<<(int)(N / 4), 256, 0, stream>>>(x, pool, inv_norm, scores, D, n);
    rank_kernel<<<B, n, (size_t)n * sizeof(double), stream>>>(
        scores, nodemap, perm_int, out, o2, o3, n, k);
    gather_kernel<<<(int)((long)B * k / 4), 256, 0, stream>>>(
        x, scores, perm_int, out + o0, D);

    bool vec_ok = (E % 4 == 0) && (o1 % 4 == 0) && ((o1 + E) % 4 == 0) && (o4 % 4 == 0);
    if (vec_ok) {
        long E4 = E / 4;
        edge_kernel4<<<(int)((E4 + 255) / 256), 256, 0, stream>>>(
            (const int4*)ei, (const int4*)(ei + E), nodemap,
            (float4*)(out + o1), (float4*)(out + o1 + E), (float4*)(out + o4), E4);
    } else {
        edge_kernel<<<(int)((E + 255) / 256), 256, 0, stream>>>(
            ei, nodemap, out, o1, o4, E);
    }
}

// Round 3
// 86.189 us; speedup vs baseline: 1.4595x; 1.1953x over previous
//
#include <hip/hip_runtime.h>
#include <math.h>

// ---------------------------------------------------------------------------
// CAGPool layer, MI355X. Outputs concatenated flat as float32 values:
//   [0]      : x_out          [B*k, D]
//   [o1]     : edge_index_new [2, E]  (ids as floats, -1 for dropped)
//   [o2]     : batch_out      [B*k]
//   [o3]     : perm           [B*k]
//   [o4]     : valid          [E]   (0.0 / 1.0)
//
// Ordering must match jax.lax.top_k exactly (descending score, ties -> lower
// index). Scores computed in float64: inv_norm is a positive per-graph
// constant, so ranking is decided by the exact f64 dot products.
// ---------------------------------------------------------------------------

// --- fast score: fused norm, 2 nodes/wave, 8 nodes/block (needs n%8==0) ----
__global__ void score_fused_kernel(const float4* __restrict__ x4,
                                   const float4* __restrict__ pool4,
                                   double* __restrict__ scores,
                                   int nv, int n) {      // nv = D/4
    int w = threadIdx.x >> 6;                 // wave 0..3
    int l = threadIdx.x & 63;
    int nodeA = blockIdx.x * 8 + w * 2;
    int nodeB = nodeA + 1;
    int b = nodeA / n;                        // whole block in one graph (n%8==0)
    const float4* pr = pool4 + (size_t)b * nv;
    const float4* xa = x4 + (size_t)nodeA * nv;
    const float4* xb = x4 + (size_t)nodeB * nv;
    double nn = 0.0, da = 0.0, db = 0.0;
    for (int j = l; j < nv; j += 64) {
        float4 pv = pr[j];
        float4 va = xa[j];
        float4 vb = xb[j];
        double px = pv.x, py = pv.y, pz = pv.z, pw = pv.w;
        nn += px * px + py * py + pz * pz + pw * pw;
        da += (double)va.x * px + (double)va.y * py
            + (double)va.z * pz + (double)va.w * pw;
        db += (double)vb.x * px + (double)vb.y * py
            + (double)vb.z * pz + (double)vb.w * pw;
    }
    // three independent butterfly chains -> good ILP
    for (int off = 32; off > 0; off >>= 1) {
        nn += __shfl_xor(nn, off, 64);
        da += __shfl_xor(da, off, 64);
        db += __shfl_xor(db, off, 64);
    }
    if (l == 0) {
        double inv = 1.0 / sqrt(nn);
        scores[nodeA] = da * inv;
        scores[nodeB] = db * inv;
    }
}

// --- fallback norm + score (general sizes) ----------------------------------
__global__ void norm_kernel(const float* __restrict__ pool,
                            double* __restrict__ inv_norm, int D) {
    int b = blockIdx.x;
    int l = threadIdx.x;
    double acc = 0.0;
    for (int j = l; j < D; j += 64) {
        double v = (double)pool[(size_t)b * D + j];
        acc += v * v;
    }
    for (int off = 32; off > 0; off >>= 1) acc += __shfl_down(acc, off, 64);
    if (l == 0) inv_norm[b] = 1.0 / sqrt(acc);
}

__global__ void score_kernel(const float* __restrict__ x,
                             const float* __restrict__ pool,
                             const double* __restrict__ inv_norm,
                             double* __restrict__ scores,
                             int D, int n) {
    int node = blockIdx.x * 4 + (threadIdx.x >> 6);
    int l = threadIdx.x & 63;
    int b = node / n;
    const float* xr = x + (size_t)node * D;
    const float* pr = pool + (size_t)b * D;
    double acc = 0.0;
    for (int j = l; j < D; j += 64)
        acc += (double)xr[j] * (double)pr[j];
    for (int off = 32; off > 0; off >>= 1) acc += __shfl_down(acc, off, 64);
    if (l == 0) scores[node] = acc * inv_norm[b];
}

// --- rank: per-graph exact top-k (O(n^2) count), write maps -----------------
__global__ void rank_kernel(const double* __restrict__ scores,
                            int* __restrict__ nodemap,
                            int* __restrict__ perm_int,
                            float* __restrict__ out,
                            long off_batch, long off_perm,
                            int n, int k) {
    extern __shared__ double s[];
    int b = blockIdx.x;
    int t = threadIdx.x;                  // block = n threads
    int gid = b * n + t;
    double st = scores[gid];
    s[t] = st;
    __syncthreads();
    int rank = 0;
#pragma unroll 8
    for (int j = 0; j < n; ++j) {
        double sj = s[j];
        rank += (int)((sj > st) || (sj == st && j < t));
    }
    if (rank < k) {
        int p = b * k + rank;
        nodemap[gid] = p;
        perm_int[p] = gid;
        out[off_batch + p] = (float)b;
        out[off_perm + p]  = (float)gid;
    } else {
        nodemap[gid] = -1;
    }
}

// --- fused output: gather (blocks < GA) + edge remap w/ LDS nodemap ---------
__global__ void out_kernel(const float4* __restrict__ x4,
                           const double* __restrict__ scores,
                           const int* __restrict__ perm_int,
                           const int4* __restrict__ ei_src,
                           const int4* __restrict__ ei_dst,
                           const int* __restrict__ nodemap,
                           float4* __restrict__ out0,
                           float4* __restrict__ out_row,
                           float4* __restrict__ out_col,
                           float4* __restrict__ out_valid,
                           int nv, int GA, long epg4, int n) {
    extern __shared__ int smem[];
    int bid = blockIdx.x;
    if (bid < GA) {
        // ---- x_out gather: 4 waves, 1 row each ----
        int w = threadIdx.x >> 6, l = threadIdx.x & 63;
        int p = bid * 4 + w;
        int gid = perm_int[p];
        double sc = scores[gid];
        float g = (float)(1.0 / (1.0 + exp(-sc)));
        const float4* xr = x4 + (size_t)gid * nv;
        float4* orow = out0 + (size_t)p * nv;
        for (int j = l; j < nv; j += 64) {
            float4 v = xr[j];
            v.x *= g; v.y *= g; v.z *= g; v.w *= g;
            orow[j] = v;
        }
    } else {
        // ---- edges: 256 int4/block = 1024 edges, all in one graph ----
        long blk = bid - GA;
        long e4base = blk * 256;
        long g = e4base / epg4;
        int base = (int)(g * (long)n);
        for (int i = threadIdx.x; i < n; i += 256)
            smem[i] = nodemap[base + i];
        __syncthreads();
        long e = e4base + threadIdx.x;
        int4 s = ei_src[e];
        int4 d = ei_dst[e];
        int r0 = smem[s.x - base], r1 = smem[s.y - base];
        int r2 = smem[s.z - base], r3 = smem[s.w - base];
        int c0 = smem[d.x - base], c1 = smem[d.y - base];
        int c2 = smem[d.z - base], c3 = smem[d.w - base];
        bool v0 = (r0 >= 0) & (c0 >= 0);
        bool v1 = (r1 >= 0) & (c1 >= 0);
        bool v2 = (r2 >= 0) & (c2 >= 0);
        bool v3 = (r3 >= 0) & (c3 >= 0);
        float4 rv = { v0 ? (float)r0 : -1.0f, v1 ? (float)r1 : -1.0f,
                      v2 ? (float)r2 : -1.0f, v3 ? (float)r3 : -1.0f };
        float4 cv = { v0 ? (float)c0 : -1.0f, v1 ? (float)c1 : -1.0f,
                      v2 ? (float)c2 : -1.0f, v3 ? (float)c3 : -1.0f };
        float4 vv = { v0 ? 1.0f : 0.0f, v1 ? 1.0f : 0.0f,
                      v2 ? 1.0f : 0.0f, v3 ? 1.0f : 0.0f };
        out_row[e]   = rv;
        out_col[e]   = cv;
        out_valid[e] = vv;
    }
}

// --- fallback gather / edge (general sizes) ----------------------------------
__global__ void gather_kernel(const float* __restrict__ x,
                              const double* __restrict__ scores,
                              const int* __restrict__ perm_int,
                              float* __restrict__ out0, int D) {
    int p = blockIdx.x * 4 + (threadIdx.x >> 6);
    int l = threadIdx.x & 63;
    int gid = perm_int[p];
    double sc = scores[gid];
    float g = (float)(1.0 / (1.0 + exp(-sc)));
    const float* xr = x + (size_t)gid * D;
    float* orow = out0 + (size_t)p * D;
    for (int j = l; j < D; j += 64) orow[j] = xr[j] * g;
}

__global__ void edge_kernel(const int* __restrict__ ei,
                            const int* __restrict__ nodemap,
                            float* __restrict__ out,
                            long off_e, long off_valid, long E) {
    long e = (long)blockIdx.x * blockDim.x + threadIdx.x;
    if (e >= E) return;
    int r = nodemap[ei[e]];
    int c = nodemap[ei[E + e]];
    bool valid = (r >= 0) && (c >= 0);
    out[off_e + e]     = valid ? (float)r : -1.0f;
    out[off_e + E + e] = valid ? (float)c : -1.0f;
    out[off_valid + e] = valid ? 1.0f : 0.0f;
}

extern "C" void kernel_launch(void* const* d_in, const int* in_sizes, int n_in,
                              void* d_out, int out_size, void* d_ws, size_t ws_size,
                              hipStream_t stream) {
    const float* x    = (const float*)d_in[0];
    const int*   ei   = (const int*)d_in[1];
    const float* pool = (const float*)d_in[3];

    const int B = in_sizes[4];
    const int D = in_sizes[3] / B;
    const long N = (long)in_sizes[0] / D;
    const long E = (long)in_sizes[1] / 2;
    const int n = (int)(N / B);
    const int k = (n + 1) / 2;            // ceil(0.5 * n)
    const long Eg = E / B;                // edges per graph

    // workspace layout
    char* ws = (char*)d_ws;
    double* scores   = (double*)ws;                         ws += (size_t)N * 8;
    double* inv_norm = (double*)ws;                         ws += (size_t)B * 8;
    int*    nodemap  = (int*)ws;                            ws += (size_t)N * 4;
    int*    perm_int = (int*)ws;

    float* out = (float*)d_out;
    const long o0 = 0;                       // x_out [B*k, D]
    const long o1 = o0 + (long)B * k * D;    // edge_index_new [2, E]
    const long o2 = o1 + 2 * E;              // batch_out [B*k]
    const long o3 = o2 + (long)B * k;        // perm [B*k]
    const long o4 = o3 + (long)B * k;        // valid [E]

    // ---- stage 1: scores ----
    if ((n % 8 == 0) && (D % 4 == 0)) {
        score_fused_kernel<<<(int)(N / 8), 256, 0, stream>>>(
            (const float4*)x, (const float4*)pool, scores, D / 4, n);
    } else {
        norm_kernel<<<B, 64, 0, stream>>>(pool, inv_norm, D);
        score_kernel<<<(int)(N / 4), 256, 0, stream>>>(
            x, pool, inv_norm, scores, D, n);
    }

    // ---- stage 2: exact top-k ranks ----
    rank_kernel<<<B, n, (size_t)n * sizeof(double), stream>>>(
        scores, nodemap, perm_int, out, o2, o3, n, k);

    // ---- stage 3: gather + edges ----
    bool fused_ok = (D % 4 == 0) && ((long)B * k % 4 == 0) &&
                    (E % 1024 == 0) && (Eg % 1024 == 0) &&
                    (o1 % 4 == 0) && ((o1 + E) % 4 == 0) && (o4 % 4 == 0);
    if (fused_ok) {
        int GA = (int)((long)B * k / 4);
        int GB = (int)(E / 1024);
        out_kernel<<<GA + GB, 256, (size_t)n * sizeof(int), stream>>>(
            (const float4*)x, scores, perm_int,
            (const int4*)ei, (const int4*)(ei + E), nodemap,
            (float4*)(out + o0), (float4*)(out + o1),
            (float4*)(out + o1 + E), (float4*)(out + o4),
            D / 4, GA, Eg / 4, n);
    } else {
        gather_kernel<<<(int)((long)B * k / 4), 256, 0, stream>>>(
            x, scores, perm_int, out + o0, D);
        edge_kernel<<<(int)((E + 255) / 256), 256, 0, stream>>>(
            ei, nodemap, out, o1, o4, E);
    }
}

// Round 4
// 84.265 us; speedup vs baseline: 1.4928x; 1.0228x over previous
//
#include <hip/hip_runtime.h>
#include <math.h>

// ---------------------------------------------------------------------------
// CAGPool layer, MI355X. Outputs concatenated flat as float32 values:
//   [0]      : x_out          [B*k, D]
//   [o1]     : edge_index_new [2, E]  (ids as floats, -1 for dropped)
//   [o2]     : batch_out      [B*k]
//   [o3]     : perm           [B*k]
//   [o4]     : valid          [E]   (0.0 / 1.0)
//
// Ordering must match jax.lax.top_k exactly (descending score, ties -> lower
// index). Scores computed in float64: inv_norm is a positive per-graph
// constant, so ranking is decided by the exact f64 dot products.
//
// Structure (fast path, D==256, n%64==0):
//   kernel 1: score+rank fused — one 1024-thread block per graph. 16 waves
//             compute all n scores into LDS (4 nodes/iter, 4-way ILP on the
//             f64 butterfly chains), then threads t<n rank in-block and emit
//             nodemap/perm/batch/gate.
//   kernel 2: out_kernel — gather x_out rows (gate pre-computed f32) +
//             edge remap with per-graph nodemap staged in LDS.
// ---------------------------------------------------------------------------

__global__ __launch_bounds__(1024)
void score_rank_kernel(const float4* __restrict__ x4,
                       const float4* __restrict__ pool4,
                       int* __restrict__ nodemap,
                       int* __restrict__ perm_int,
                       float* __restrict__ gate,
                       float* __restrict__ out,
                       long off_batch, long off_perm,
                       int n, int k) {
    extern __shared__ double s[];            // n doubles
    int b = blockIdx.x;
    int t = threadIdx.x;
    int w = t >> 6, l = t & 63;
    int nw = blockDim.x >> 6;                // 16 waves

    // pool row (D=256 -> exactly one float4 per lane) + norm, once per wave
    float4 pv = pool4[(size_t)b * 64 + l];
    double px = pv.x, py = pv.y, pz = pv.z, pw = pv.w;
    double nn = px * px + py * py + pz * pz + pw * pw;
    for (int off = 32; off > 0; off >>= 1) nn += __shfl_xor(nn, off, 64);
    double inv = 1.0 / sqrt(nn);             // all lanes hold it

    int npw = n / nw;                        // nodes per wave (multiple of 4)
    const float4* xg = x4 + ((size_t)b * n + (size_t)w * npw) * 64;
    for (int i = 0; i < npw; i += 4) {
        const float4* xa = xg + (size_t)i * 64;
        float4 va = xa[l], vb = xa[64 + l], vc = xa[128 + l], vd = xa[192 + l];
        double da = (double)va.x * px + (double)va.y * py
                  + (double)va.z * pz + (double)va.w * pw;
        double db = (double)vb.x * px + (double)vb.y * py
                  + (double)vb.z * pz + (double)vb.w * pw;
        double dc = (double)vc.x * px + (double)vc.y * py
                  + (double)vc.z * pz + (double)vc.w * pw;
        double dd = (double)vd.x * px + (double)vd.y * py
                  + (double)vd.z * pz + (double)vd.w * pw;
        for (int off = 32; off > 0; off >>= 1) {   // 4 independent chains
            da += __shfl_xor(da, off, 64);
            db += __shfl_xor(db, off, 64);
            dc += __shfl_xor(dc, off, 64);
            dd += __shfl_xor(dd, off, 64);
        }
        if (l == 0) {
            int base = w * npw + i;
            s[base]     = da * inv;
            s[base + 1] = db * inv;
            s[base + 2] = dc * inv;
            s[base + 3] = dd * inv;
        }
    }
    __syncthreads();

    if (t < n) {
        double st = s[t];
        int rank = 0;
#pragma unroll 8
        for (int j = 0; j < n; ++j) {
            double sj = s[j];
            rank += (int)((sj > st) || (sj == st && j < t));
        }
        int gid = b * n + t;
        if (rank < k) {
            int p = b * k + rank;
            nodemap[gid] = p;
            perm_int[p] = gid;
            gate[p] = (float)(1.0 / (1.0 + exp(-st)));
            out[off_batch + p] = (float)b;
            out[off_perm + p]  = (float)gid;
        } else {
            nodemap[gid] = -1;
        }
    }
}

// --- fused output: gather (blocks < GA) + edge remap w/ LDS nodemap ---------
// edge blocks: 2048 edges each (2 int4 per thread), all within one graph.
__global__ void out_kernel(const float4* __restrict__ x4,
                           const float* __restrict__ gate,
                           const int* __restrict__ perm_int,
                           const int4* __restrict__ ei_src,
                           const int4* __restrict__ ei_dst,
                           const int* __restrict__ nodemap,
                           float4* __restrict__ out0,
                           float4* __restrict__ out_row,
                           float4* __restrict__ out_col,
                           float4* __restrict__ out_valid,
                           int nv, int GA, long epg4, int n) {
    extern __shared__ int smem[];
    int bid = blockIdx.x;
    if (bid < GA) {
        // ---- x_out gather: 4 waves, 1 row each ----
        int w = threadIdx.x >> 6, l = threadIdx.x & 63;
        int p = bid * 4 + w;
        int gid = perm_int[p];
        float g = gate[p];
        const float4* xr = x4 + (size_t)gid * nv;
        float4* orow = out0 + (size_t)p * nv;
        for (int j = l; j < nv; j += 64) {
            float4 v = xr[j];
            v.x *= g; v.y *= g; v.z *= g; v.w *= g;
            orow[j] = v;
        }
    } else {
        long blk = bid - GA;
        long e4base = blk * 512;                  // int4 units, 2048 edges
        long g = e4base / epg4;
        int base = (int)(g * (long)n);
        for (int i = threadIdx.x; i < n; i += 256)
            smem[i] = nodemap[base + i];
        __syncthreads();
#pragma unroll
        for (int half = 0; half < 2; ++half) {
            long e = e4base + half * 256 + threadIdx.x;
            int4 sv = ei_src[e];
            int4 dv = ei_dst[e];
            int r0 = smem[sv.x - base], r1 = smem[sv.y - base];
            int r2 = smem[sv.z - base], r3 = smem[sv.w - base];
            int c0 = smem[dv.x - base], c1 = smem[dv.y - base];
            int c2 = smem[dv.z - base], c3 = smem[dv.w - base];
            bool v0 = (r0 >= 0) & (c0 >= 0);
            bool v1 = (r1 >= 0) & (c1 >= 0);
            bool v2 = (r2 >= 0) & (c2 >= 0);
            bool v3 = (r3 >= 0) & (c3 >= 0);
            float4 rv = { v0 ? (float)r0 : -1.0f, v1 ? (float)r1 : -1.0f,
                          v2 ? (float)r2 : -1.0f, v3 ? (float)r3 : -1.0f };
            float4 cv = { v0 ? (float)c0 : -1.0f, v1 ? (float)c1 : -1.0f,
                          v2 ? (float)c2 : -1.0f, v3 ? (float)c3 : -1.0f };
            float4 vv = { v0 ? 1.0f : 0.0f, v1 ? 1.0f : 0.0f,
                          v2 ? 1.0f : 0.0f, v3 ? 1.0f : 0.0f };
            out_row[e]   = rv;
            out_col[e]   = cv;
            out_valid[e] = vv;
        }
    }
}

// ======================= fallback path (general sizes) ======================
__global__ void norm_kernel(const float* __restrict__ pool,
                            double* __restrict__ inv_norm, int D) {
    int b = blockIdx.x;
    int l = threadIdx.x;
    double acc = 0.0;
    for (int j = l; j < D; j += 64) {
        double v = (double)pool[(size_t)b * D + j];
        acc += v * v;
    }
    for (int off = 32; off > 0; off >>= 1) acc += __shfl_down(acc, off, 64);
    if (l == 0) inv_norm[b] = 1.0 / sqrt(acc);
}

__global__ void score_kernel(const float* __restrict__ x,
                             const float* __restrict__ pool,
                             const double* __restrict__ inv_norm,
                             double* __restrict__ scores,
                             int D, int n) {
    int node = blockIdx.x * 4 + (threadIdx.x >> 6);
    int l = threadIdx.x & 63;
    int b = node / n;
    const float* xr = x + (size_t)node * D;
    const float* pr = pool + (size_t)b * D;
    double acc = 0.0;
    for (int j = l; j < D; j += 64)
        acc += (double)xr[j] * (double)pr[j];
    for (int off = 32; off > 0; off >>= 1) acc += __shfl_down(acc, off, 64);
    if (l == 0) scores[node] = acc * inv_norm[b];
}

__global__ void rank_kernel(const double* __restrict__ scores,
                            int* __restrict__ nodemap,
                            int* __restrict__ perm_int,
                            float* __restrict__ out,
                            long off_batch, long off_perm,
                            int n, int k) {
    extern __shared__ double s[];
    int b = blockIdx.x;
    int t = threadIdx.x;
    int gid = b * n + t;
    double st = scores[gid];
    s[t] = st;
    __syncthreads();
    int rank = 0;
    for (int j = 0; j < n; ++j) {
        double sj = s[j];
        rank += (int)((sj > st) || (sj == st && j < t));
    }
    if (rank < k) {
        int p = b * k + rank;
        nodemap[gid] = p;
        perm_int[p] = gid;
        out[off_batch + p] = (float)b;
        out[off_perm + p]  = (float)gid;
    } else {
        nodemap[gid] = -1;
    }
}

__global__ void gather_kernel(const float* __restrict__ x,
                              const double* __restrict__ scores,
                              const int* __restrict__ perm_int,
                              float* __restrict__ out0, int D) {
    int p = blockIdx.x;
    int l = threadIdx.x;
    int gid = perm_int[p];
    double sc = scores[gid];
    float g = (float)(1.0 / (1.0 + exp(-sc)));
    const float* xr = x + (size_t)gid * D;
    float* orow = out0 + (size_t)p * D;
    for (int j = l; j < D; j += 64) orow[j] = xr[j] * g;
}

__global__ void edge_kernel(const int* __restrict__ ei,
                            const int* __restrict__ nodemap,
                            float* __restrict__ out,
                            long off_e, long off_valid, long E) {
    long e = (long)blockIdx.x * blockDim.x + threadIdx.x;
    if (e >= E) return;
    int r = nodemap[ei[e]];
    int c = nodemap[ei[E + e]];
    bool valid = (r >= 0) && (c >= 0);
    out[off_e + e]     = valid ? (float)r : -1.0f;
    out[off_e + E + e] = valid ? (float)c : -1.0f;
    out[off_valid + e] = valid ? 1.0f : 0.0f;
}

// ============================================================================
extern "C" void kernel_launch(void* const* d_in, const int* in_sizes, int n_in,
                              void* d_out, int out_size, void* d_ws, size_t ws_size,
                              hipStream_t stream) {
    const float* x    = (const float*)d_in[0];
    const int*   ei   = (const int*)d_in[1];
    const float* pool = (const float*)d_in[3];

    const int B = in_sizes[4];
    const int D = in_sizes[3] / B;
    const long N = (long)in_sizes[0] / D;
    const long E = (long)in_sizes[1] / 2;
    const int n = (int)(N / B);
    const int k = (n + 1) / 2;            // ceil(0.5 * n)
    const long Eg = E / B;                // edges per graph

    // workspace layout
    char* ws = (char*)d_ws;
    double* scores   = (double*)ws;                         ws += (size_t)N * 8;
    double* inv_norm = (double*)ws;                         ws += (size_t)B * 8;
    int*    nodemap  = (int*)ws;                            ws += (size_t)N * 4;
    int*    perm_int = (int*)ws;                            ws += (size_t)B * ((N/B+1)/2) * 4;
    float*  gate     = (float*)ws;

    float* out = (float*)d_out;
    const long o0 = 0;                       // x_out [B*k, D]
    const long o1 = o0 + (long)B * k * D;    // edge_index_new [2, E]
    const long o2 = o1 + 2 * E;              // batch_out [B*k]
    const long o3 = o2 + (long)B * k;        // perm [B*k]
    const long o4 = o3 + (long)B * k;        // valid [E]

    bool fused_sr_ok = (D == 256) && (n % 64 == 0) && (n <= 1024);
    bool fused_out_ok = fused_sr_ok && ((long)B * k % 4 == 0) &&
                        (E % 2048 == 0) && (Eg % 2048 == 0) &&
                        (o1 % 4 == 0) && ((o1 + E) % 4 == 0) && (o4 % 4 == 0);

    if (fused_out_ok) {
        // stage 1: score + rank, one block per graph
        score_rank_kernel<<<B, 1024, (size_t)n * sizeof(double), stream>>>(
            (const float4*)x, (const float4*)pool,
            nodemap, perm_int, gate, out, o2, o3, n, k);
        // stage 2: gather + edges
        int GA = (int)((long)B * k / 4);
        int GB = (int)(E / 2048);
        out_kernel<<<GA + GB, 256, (size_t)n * sizeof(int), stream>>>(
            (const float4*)x, gate, perm_int,
            (const int4*)ei, (const int4*)(ei + E), nodemap,
            (float4*)(out + o0), (float4*)(out + o1),
            (float4*)(out + o1 + E), (float4*)(out + o4),
            D / 4, GA, Eg / 4, n);
    } else {
        norm_kernel<<<B, 64, 0, stream>>>(pool, inv_norm, D);
        score_kernel<<<(int)(N / 4), 256, 0, stream>>>(
            x, pool, inv_norm, scores, D, n);
        rank_kernel<<<B, n, (size_t)n * sizeof(double), stream>>>(
            scores, nodemap, perm_int, out, o2, o3, n, k);
        gather_kernel<<<(int)((long)B * k), 64, 0, stream>>>(
            x, scores, perm_int, out + o0, D);
        edge_kernel<<<(int)((E + 255) / 256), 256, 0, stream>>>(
            ei, nodemap, out, o1, o4, E);
    }
}